// Round 12
// baseline (400.101 us; speedup 1.0000x reference)
//
#include <hip/hip_runtime.h>
#include <hip/hip_cooperative_groups.h>

namespace cg = cooperative_groups;

#define N_NODES 100000
#define N_EDGES 800000
#define NBY    ((N_NODES + 255) / 256)             // 391 (fallback path)
#define HBLK   ((N_EDGES + 255) / 256)             // 3125 (fallback path)
#define OVF_CAP 65536
#define GA     250                                 // fallback phase-A blocks
#define CHUNK  3200                                // fallback edges/block
#define NBINS  512
#define NPB    196                                 // nodes per bin (512*196 = 100352)
#define CAPB   2048                                // slots/bin (mean 1562, sigma ~40)
#define GB_T   1024                                // gather block threads
#define CURSTRIDE 64                               // ints; 256B per cursor line
// fused config: 512 blocks x 1024 thr = 2 blocks/CU x 256 CU (exact residency)
#define FB     512
#define FT     1024
#define PAB    256                                 // phase-A active blocks in fused kernel
#define PACHUNK 3125                               // 256*3125 = 800000 exactly
// record: .x = sj*512 + (kx0*4+ky0)*32 ; .y = fx12 | fy12<<12 | local<<24

__device__ __forceinline__ unsigned short f2bf(float f) {
    union { float f; unsigned u; } v; v.f = f;
    unsigned u = v.u;
    return (unsigned short)((u + 0x7FFFu + ((u >> 16) & 1u)) >> 16);  // RNE
}
__device__ __forceinline__ float bflo(unsigned u) {
    union { unsigned u; float f; } v; v.u = u << 16; return v.f;
}
__device__ __forceinline__ float bfhi(unsigned u) {
    union { unsigned u; float f; } v; v.u = u & 0xFFFF0000u; return v.f;
}

// ================= R10: single cooperative kernel =================
// {zero cursors + phase A pass1} -> grid.sync -> {pass2+pass3} -> grid.sync
// -> phase B (R9 gather logic, bin = blockIdx.x).
// LDS: one 52.6KB buffer; phase A arrays alias phase B's sorted/u_buf regions.
__global__ __launch_bounds__(FT, 8) void fused_all(
    int* __restrict__ cursor, uint2* __restrict__ bkt,
    const float* __restrict__ x, const float* __restrict__ W,
    float* __restrict__ out, int* __restrict__ ovfCnt, int* __restrict__ ovf,
    const float* __restrict__ edge_attr, const int* __restrict__ ei,
    const int* __restrict__ ej) {
    cg::grid_group grid = cg::this_grid();
    const int b = blockIdx.x;
    const int tid = threadIdx.x;

    __shared__ __align__(16) char SM[52576];
    // phase B layout
    uint2* sorted = (uint2*)SM;                    // 16384 B
    uint2* rawS   = (uint2*)(SM + 16384);          // stage-1 record staging (16384)
    float* Wl     = (float*)(SM + 16384);          // padded W [16][16][20] (20480)
    float* tile   = (float*)(SM + 36864);          // 12544 B
    int*   h      = (int*)(SM + 49408);            // 784 B
    int*   st     = (int*)(SM + 50192);
    int*   en     = (int*)(SM + 50976);
    int*   cur    = (int*)(SM + 51760);
    int*   wsum   = (int*)(SM + 52544);
    // phase A aliases (dead before phase B writes these regions)
    unsigned* rawA = (unsigned*)SM;                // 12500 B
    unsigned* rawB = (unsigned*)(SM + 12512);      // 12500 B
    short*  rawBin = (short*)(SM + 25024);         // 6250 B
    int*    hist   = (int*)(SM + 31280);           // 2048 B

    // zero this block's cursor line + ovfCnt (device-scope; visible post-sync1)
    if (tid == 0) {
        atomicExch(&cursor[b * CURSTRIDE], 0);
        if (b == 0) atomicExch(ovfCnt, 0);
    }
    for (int j = tid; j < NPB; j += FT) h[j] = 0;  // h not aliased by phase A

    // ---- phase A pass 1 on blocks [0, PAB): block-local only ----
    if (b < PAB) {
        if (tid < NBINS) hist[tid] = 0;
        __syncthreads();
        const int base = b * PACHUNK;
        for (int i = 0; i < PACHUNK; i += FT) {
            const int j = i + tid;
            if (j >= PACHUNK) continue;            // 3125 % 1024 != 0 guard
            const int e = base + j;
            short binS = -1;
            const int di = ei[e];
            const int sj = ej[e];
            if (di != sj) {                        // centerIgnore
                const float2 ea = ((const float2*)edge_attr)[e];
                float ux = fminf(fmaxf(ea.x, -1.f), 1.f);
                float uy = fminf(fmaxf(ea.y, -1.f), 1.f);
                float tx = (ux + 1.f) * 1.5f;
                float ty = (uy + 1.f) * 1.5f;
                int kx0 = min((int)tx, 2);
                int ky0 = min((int)ty, 2);
                float fx = tx - (float)kx0;
                float fy = ty - (float)ky0;
                unsigned fx12 = (unsigned)(fx * 4095.f + 0.5f);
                unsigned fy12 = (unsigned)(fy * 4095.f + 0.5f);
                const int bn = di / NPB;
                const unsigned local = (unsigned)(di - bn * NPB);   // < 196
                rawA[j] = (unsigned)(sj * 512 + (kx0 * 4 + ky0) * 32);
                rawB[j] = fx12 | (fy12 << 12) | (local << 24);
                binS = (short)bn;
                atomicAdd(&hist[bn], 1);
            }
            rawBin[j] = binS;
        }
    }

    grid.sync();   // all cursors zeroed; all pass-1 LDS records built

    if (b < PAB) {
        // pass 2: one returning global atomic per non-empty (block,bin)
        if (tid < NBINS) {
            const int c = hist[tid];
            int g = 0;
            if (c > 0) g = atomicAdd(&cursor[tid * CURSTRIDE], c);
            hist[tid] = tid * CAPB + g;
        }
        __syncthreads();
        // pass 3: replay from LDS, slot via LDS atomic, 8B global store
        const int base = b * PACHUNK;
        for (int i = 0; i < PACHUNK; i += FT) {
            const int j = i + tid;
            if (j >= PACHUNK) continue;
            const int bn = rawBin[j];
            if (bn < 0) continue;
            const int s = atomicAdd(&hist[bn], 1);
            if (s - bn * CAPB < CAPB) {
                bkt[s] = make_uint2(rawA[j], rawB[j]);
            } else {
                const int o = atomicAdd(ovfCnt, 1);
                if (o < OVF_CAP) ovf[o] = base + j;
            }
        }
    }

    grid.sync();   // all bkt/ovf/cursor writes visible (release/acquire fences)

    // ================= phase B: bin = b (R9-verified logic) =================
    const int bin = b;
    const int cnt = min(cursor[bin * CURSTRIDE], CAPB);
    const int pad = (cnt + NPB <= CAPB) ? 1 : 0;   // stagger only if slots allow
    const uint2* rb = bkt + (size_t)bin * CAPB;

    // stage 1: single global read of records -> LDS rawS[], histogram
    for (int p = tid; p < cnt; p += FT) {
        uint2 r = rb[p];
        rawS[p] = r;
        atomicAdd(&h[r.y >> 24], 1);
    }
    __syncthreads();

    // stage 2: wave64 shfl_up scan + 4-wave combine (2 barriers)
    const int lane = tid & 63;
    const int wid  = tid >> 6;
    int c0 = 0, v = 0;
    if (tid < 256) {                               // waves 0..3 cover NPB=196
        c0 = (tid < NPB) ? h[tid] : 0;
        v = c0;
#pragma unroll
        for (int off = 1; off < 64; off <<= 1) {
            int u = __shfl_up(v, off);
            if (lane >= off) v += u;
        }
        if (lane == 63) wsum[wid] = v;
    }
    __syncthreads();
    if (tid < NPB) {
        int pfx = 0;
#pragma unroll
        for (int w = 0; w < 4; ++w)
            if (w < wid) pfx += wsum[w];
        const int incl = v + pfx;
        const int sh = tid * pad;                  // bank stagger (+node)
        en[tid]  = incl + sh;
        st[tid]  = incl - c0 + sh;
        cur[tid] = incl - c0 + sh;
    }
    __syncthreads();

    // stage 3: scatter into (staggered) sorted order -- LDS -> LDS
    for (int p = tid; p < cnt; p += FT) {
        uint2 r = rawS[p];
        int pos = atomicAdd(&cur[r.y >> 24], 1);
        sorted[pos] = r;
    }
    __syncthreads();

    // stage W: rawS dead; stage W into padded Wl (same buffer)
    {
        float4 w = ((const float4*)W)[tid];
        const int k = tid >> 6, i2 = (tid >> 2) & 15, o4 = tid & 3;
        *(float4*)&Wl[k * 320 + i2 * 20 + o4 * 4] = w;
    }
    __syncthreads();

    // stage 4: input-space accumulation, 4 threads/node (784 active)
    const float U = 1.f / 4095.f;
    const float S = 1.f / 128.f;                   // OUTPUT_SCALING
    if (tid < 4 * NPB) {
        const int node = tid >> 2;
        const int q4 = tid & 3;
        float t[16][4];
#pragma unroll
        for (int k = 0; k < 16; ++k)
#pragma unroll
            for (int i = 0; i < 4; ++i) t[k][i] = 0.f;

        const int lo = st[node], hi2 = en[node];
        uint2 m = make_uint2(0u, 0u);
        float4 xv = make_float4(0.f, 0.f, 0.f, 0.f);
        if (lo < hi2) {
            m = sorted[lo];
            xv = ((const float4*)x)[(m.x >> 9) * 4 + q4];
        }
        for (int idx = lo; idx < hi2; ++idx) {
            const uint2 mc = m;
            const float4 xc = xv;
            if (idx + 1 < hi2) {                   // prefetch next (hides L2 latency)
                m = sorted[idx + 1];
                xv = ((const float4*)x)[(m.x >> 9) * 4 + q4];
            }
            const unsigned koff = (mc.x >> 5) & 15u;
            const int kx0 = (int)(koff >> 2);
            const int ky0 = (int)(koff & 3u);
            const float fx = (float)(mc.y & 0xFFFu) * U;
            const float fy = (float)((mc.y >> 12) & 0xFFFu) * U;
            float wx[4], wy[4];
#pragma unroll
            for (int a = 0; a < 4; ++a) {
                wx[a] = (a == kx0) ? (1.f - fx) : ((a == kx0 + 1) ? fx : 0.f);
                wy[a] = (a == ky0) ? (1.f - fy) : ((a == ky0 + 1) ? fy : 0.f);
            }
            const float xr[4] = {xc.x, xc.y, xc.z, xc.w};
#pragma unroll
            for (int kx = 0; kx < 4; ++kx)
#pragma unroll
                for (int ky = 0; ky < 4; ++ky) {
                    const float w = wx[kx] * wy[ky];
#pragma unroll
                    for (int i = 0; i < 4; ++i)
                        t[kx * 4 + ky][i] = fmaf(w, xr[i], t[kx * 4 + ky][i]);
                }
        }

        // epilogue: contract t with Wl (padded stride 20 -> 2-way max)
        float po[16];
#pragma unroll
        for (int o = 0; o < 16; ++o) po[o] = 0.f;
#pragma unroll
        for (int k = 0; k < 16; ++k)
#pragma unroll
            for (int il = 0; il < 4; ++il) {
                const float tv = t[k][il];
                const float4* wr = (const float4*)&Wl[k * 320 + (q4 * 4 + il) * 20];
                const float4 w0 = wr[0], w1 = wr[1], w2 = wr[2], w3 = wr[3];
                po[0]  = fmaf(tv, w0.x, po[0]);  po[1]  = fmaf(tv, w0.y, po[1]);
                po[2]  = fmaf(tv, w0.z, po[2]);  po[3]  = fmaf(tv, w0.w, po[3]);
                po[4]  = fmaf(tv, w1.x, po[4]);  po[5]  = fmaf(tv, w1.y, po[5]);
                po[6]  = fmaf(tv, w1.z, po[6]);  po[7]  = fmaf(tv, w1.w, po[7]);
                po[8]  = fmaf(tv, w2.x, po[8]);  po[9]  = fmaf(tv, w2.y, po[9]);
                po[10] = fmaf(tv, w2.z, po[10]); po[11] = fmaf(tv, w2.w, po[11]);
                po[12] = fmaf(tv, w3.x, po[12]); po[13] = fmaf(tv, w3.y, po[13]);
                po[14] = fmaf(tv, w3.z, po[14]); po[15] = fmaf(tv, w3.w, po[15]);
            }

        // reduce across the 4-lane group (lane-aligned, all active)
#pragma unroll
        for (int o = 0; o < 16; ++o) {
            po[o] += __shfl_xor(po[o], 1);
            po[o] += __shfl_xor(po[o], 2);
        }
        if (q4 == 0) {
            float* tr = &tile[node * 16];
#pragma unroll
            for (int o = 0; o < 16; ++o) tr[o] = po[o] * S;
        }
    }
    __syncthreads();

    // stage 4b: fused overflow fix-up (ovfCnt ~always 0 -> one read, skip)
    const int mv = min(*ovfCnt, OVF_CAP);
    if (mv > 0) {
        const int nlo = bin * NPB;
        const int nhi = min(nlo + NPB, N_NODES);
        for (int i = tid; i < mv; i += FT) {
            const int e = ovf[i];
            const int di = ei[e];
            if (di < nlo || di >= nhi) continue;
            const int sj = ej[e];
            const float2 ea = ((const float2*)edge_attr)[e];
            float ux = fminf(fmaxf(ea.x, -1.f), 1.f);
            float uy = fminf(fmaxf(ea.y, -1.f), 1.f);
            float tx = (ux + 1.f) * 1.5f, ty = (uy + 1.f) * 1.5f;
            int kx0 = min((int)tx, 2), ky0 = min((int)ty, 2);
            float fx = tx - (float)kx0, fy = ty - (float)ky0;
            float wgt[4] = {(1.f-fx)*(1.f-fy)*S, (1.f-fx)*fy*S, fx*(1.f-fy)*S, fx*fy*S};
            int kidx[4] = {kx0*4+ky0, kx0*4+ky0+1, (kx0+1)*4+ky0, (kx0+1)*4+ky0+1};
            const float* xj = x + (size_t)sj * 16;
            float msg[16];
#pragma unroll
            for (int o = 0; o < 16; ++o) msg[o] = 0.f;
#pragma unroll
            for (int p = 0; p < 4; ++p) {
                const float* wk = Wl + kidx[p] * 320;     // padded stride
                for (int ii = 0; ii < 16; ++ii) {
                    float xw = xj[ii] * wgt[p];
#pragma unroll
                    for (int o = 0; o < 16; ++o)
                        msg[o] = fmaf(xw, wk[ii * 20 + o], msg[o]);
                }
            }
            float* tr = &tile[(di - nlo) * 16];
#pragma unroll
            for (int o = 0; o < 16; ++o) atomicAdd(tr + o, msg[o]);
        }
        __syncthreads();
    }

    // stage 5: coalesced block store (bins own disjoint node ranges)
    const int base2 = bin * NPB * 16;
    const int lim = N_NODES * 16 - base2;
    for (int j = tid; j < NPB * 16; j += FT)
        if (j < lim) out[base2 + j] = tile[j];
}

// ================= fallback: R9 3-dispatch path (unchanged) =================
__global__ __launch_bounds__(256) void bucket_build(
    const float* __restrict__ edge_attr,
    const int* __restrict__ ei, const int* __restrict__ ej,
    int* __restrict__ cursor, uint2* __restrict__ bkt,
    int* __restrict__ ovfCnt, int* __restrict__ ovf) {
    const int b = blockIdx.x;
    __shared__ int hist[NBINS];
    __shared__ unsigned rawA[CHUNK];
    __shared__ unsigned rawB[CHUNK];
    __shared__ short rawBin[CHUNK];
    const int tid = threadIdx.x;
    for (int k = tid; k < NBINS; k += 256) hist[k] = 0;
    __syncthreads();
    const int base = b * CHUNK;
    for (int i = 0; i < CHUNK; i += 256) {
        const int j = i + tid;
        if (j >= CHUNK) continue;
        const int e = base + j;
        short binS = -1;
        if (e < N_EDGES) {
            const int di = ei[e];
            const int sj = ej[e];
            if (di != sj) {
                const float2 ea = ((const float2*)edge_attr)[e];
                float ux = fminf(fmaxf(ea.x, -1.f), 1.f);
                float uy = fminf(fmaxf(ea.y, -1.f), 1.f);
                float tx = (ux + 1.f) * 1.5f;
                float ty = (uy + 1.f) * 1.5f;
                int kx0 = min((int)tx, 2);
                int ky0 = min((int)ty, 2);
                float fx = tx - (float)kx0;
                float fy = ty - (float)ky0;
                unsigned fx12 = (unsigned)(fx * 4095.f + 0.5f);
                unsigned fy12 = (unsigned)(fy * 4095.f + 0.5f);
                const int bin = di / NPB;
                const unsigned local = (unsigned)(di - bin * NPB);
                rawA[j] = (unsigned)(sj * 512 + (kx0 * 4 + ky0) * 32);
                rawB[j] = fx12 | (fy12 << 12) | (local << 24);
                binS = (short)bin;
                atomicAdd(&hist[bin], 1);
            }
        }
        rawBin[j] = binS;
    }
    __syncthreads();
    for (int k = tid; k < NBINS; k += 256) {
        const int c = hist[k];
        int g = 0;
        if (c > 0) g = atomicAdd(&cursor[k * CURSTRIDE], c);
        hist[k] = k * CAPB + g;
    }
    __syncthreads();
    for (int i = 0; i < CHUNK; i += 256) {
        const int j = i + tid;
        if (j >= CHUNK) continue;
        const int bin = rawBin[j];
        if (bin < 0) continue;
        const int s = atomicAdd(&hist[bin], 1);
        if (s - bin * CAPB < CAPB) {
            bkt[s] = make_uint2(rawA[j], rawB[j]);
        } else {
            const int o = atomicAdd(ovfCnt, 1);
            if (o < OVF_CAP) ovf[o] = base + j;
        }
    }
}

__global__ __launch_bounds__(GB_T) void gather_conv(
    const int* __restrict__ cursor, const uint2* __restrict__ bkt,
    const float* __restrict__ x, const float* __restrict__ W,
    float* __restrict__ out,
    const int* __restrict__ ovfCnt, const int* __restrict__ ovf,
    const float* __restrict__ edge_attr, const int* __restrict__ ei,
    const int* __restrict__ ej) {
    const int bin = blockIdx.x;
    const int tid = threadIdx.x;
    __shared__ uint2 sorted[CAPB];
    __shared__ __align__(16) char u_buf[20480];
    __shared__ int h[NPB];
    __shared__ int st[NPB], en[NPB], cur[NPB];
    __shared__ int wsum[4];
    __shared__ float tile[NPB * 16];
    uint2* raw = (uint2*)u_buf;
    float* Wl  = (float*)u_buf;

    for (int j = tid; j < NPB; j += GB_T) h[j] = 0;
    __syncthreads();

    const int cnt = min(cursor[bin * CURSTRIDE], CAPB);
    const int pad = (cnt + NPB <= CAPB) ? 1 : 0;
    const uint2* rb = bkt + (size_t)bin * CAPB;

    for (int p = tid; p < cnt; p += GB_T) {
        uint2 r = rb[p];
        raw[p] = r;
        atomicAdd(&h[r.y >> 24], 1);
    }
    __syncthreads();

    const int lane = tid & 63;
    const int wid  = tid >> 6;
    int c0 = 0, v = 0;
    if (tid < 256) {
        c0 = (tid < NPB) ? h[tid] : 0;
        v = c0;
#pragma unroll
        for (int off = 1; off < 64; off <<= 1) {
            int u = __shfl_up(v, off);
            if (lane >= off) v += u;
        }
        if (lane == 63) wsum[wid] = v;
    }
    __syncthreads();
    if (tid < NPB) {
        int pfx = 0;
#pragma unroll
        for (int w = 0; w < 4; ++w)
            if (w < wid) pfx += wsum[w];
        const int incl = v + pfx;
        const int sh = tid * pad;
        en[tid]  = incl + sh;
        st[tid]  = incl - c0 + sh;
        cur[tid] = incl - c0 + sh;
    }
    __syncthreads();

    for (int p = tid; p < cnt; p += GB_T) {
        uint2 r = raw[p];
        int pos = atomicAdd(&cur[r.y >> 24], 1);
        sorted[pos] = r;
    }
    __syncthreads();

    {
        float4 w = ((const float4*)W)[tid];
        const int k = tid >> 6, i = (tid >> 2) & 15, o4 = tid & 3;
        *(float4*)&Wl[k * 320 + i * 20 + o4 * 4] = w;
    }
    __syncthreads();

    const float U = 1.f / 4095.f;
    const float S = 1.f / 128.f;
    if (tid < 4 * NPB) {
        const int node = tid >> 2;
        const int q4 = tid & 3;
        float t[16][4];
#pragma unroll
        for (int k = 0; k < 16; ++k)
#pragma unroll
            for (int i = 0; i < 4; ++i) t[k][i] = 0.f;

        const int lo = st[node], hi2 = en[node];
        uint2 m = make_uint2(0u, 0u);
        float4 xv = make_float4(0.f, 0.f, 0.f, 0.f);
        if (lo < hi2) {
            m = sorted[lo];
            xv = ((const float4*)x)[(m.x >> 9) * 4 + q4];
        }
        for (int idx = lo; idx < hi2; ++idx) {
            const uint2 mc = m;
            const float4 xc = xv;
            if (idx + 1 < hi2) {
                m = sorted[idx + 1];
                xv = ((const float4*)x)[(m.x >> 9) * 4 + q4];
            }
            const unsigned koff = (mc.x >> 5) & 15u;
            const int kx0 = (int)(koff >> 2);
            const int ky0 = (int)(koff & 3u);
            const float fx = (float)(mc.y & 0xFFFu) * U;
            const float fy = (float)((mc.y >> 12) & 0xFFFu) * U;
            float wx[4], wy[4];
#pragma unroll
            for (int a = 0; a < 4; ++a) {
                wx[a] = (a == kx0) ? (1.f - fx) : ((a == kx0 + 1) ? fx : 0.f);
                wy[a] = (a == ky0) ? (1.f - fy) : ((a == ky0 + 1) ? fy : 0.f);
            }
            const float xr[4] = {xc.x, xc.y, xc.z, xc.w};
#pragma unroll
            for (int kx = 0; kx < 4; ++kx)
#pragma unroll
                for (int ky = 0; ky < 4; ++ky) {
                    const float w = wx[kx] * wy[ky];
#pragma unroll
                    for (int i = 0; i < 4; ++i)
                        t[kx * 4 + ky][i] = fmaf(w, xr[i], t[kx * 4 + ky][i]);
                }
        }

        float po[16];
#pragma unroll
        for (int o = 0; o < 16; ++o) po[o] = 0.f;
#pragma unroll
        for (int k = 0; k < 16; ++k)
#pragma unroll
            for (int il = 0; il < 4; ++il) {
                const float tv = t[k][il];
                const float4* wr = (const float4*)&Wl[k * 320 + (q4 * 4 + il) * 20];
                const float4 w0 = wr[0], w1 = wr[1], w2 = wr[2], w3 = wr[3];
                po[0]  = fmaf(tv, w0.x, po[0]);  po[1]  = fmaf(tv, w0.y, po[1]);
                po[2]  = fmaf(tv, w0.z, po[2]);  po[3]  = fmaf(tv, w0.w, po[3]);
                po[4]  = fmaf(tv, w1.x, po[4]);  po[5]  = fmaf(tv, w1.y, po[5]);
                po[6]  = fmaf(tv, w1.z, po[6]);  po[7]  = fmaf(tv, w1.w, po[7]);
                po[8]  = fmaf(tv, w2.x, po[8]);  po[9]  = fmaf(tv, w2.y, po[9]);
                po[10] = fmaf(tv, w2.z, po[10]); po[11] = fmaf(tv, w2.w, po[11]);
                po[12] = fmaf(tv, w3.x, po[12]); po[13] = fmaf(tv, w3.y, po[13]);
                po[14] = fmaf(tv, w3.z, po[14]); po[15] = fmaf(tv, w3.w, po[15]);
            }

#pragma unroll
        for (int o = 0; o < 16; ++o) {
            po[o] += __shfl_xor(po[o], 1);
            po[o] += __shfl_xor(po[o], 2);
        }
        if (q4 == 0) {
            float* tr = &tile[node * 16];
#pragma unroll
            for (int o = 0; o < 16; ++o) tr[o] = po[o] * S;
        }
    }
    __syncthreads();

    const int m = min(*ovfCnt, OVF_CAP);
    if (m > 0) {
        const int nlo = bin * NPB;
        const int nhi = min(nlo + NPB, N_NODES);
        for (int i = tid; i < m; i += GB_T) {
            const int e = ovf[i];
            const int di = ei[e];
            if (di < nlo || di >= nhi) continue;
            const int sj = ej[e];
            const float2 ea = ((const float2*)edge_attr)[e];
            float ux = fminf(fmaxf(ea.x, -1.f), 1.f);
            float uy = fminf(fmaxf(ea.y, -1.f), 1.f);
            float tx = (ux + 1.f) * 1.5f, ty = (uy + 1.f) * 1.5f;
            int kx0 = min((int)tx, 2), ky0 = min((int)ty, 2);
            float fx = tx - (float)kx0, fy = ty - (float)ky0;
            float wgt[4] = {(1.f-fx)*(1.f-fy)*S, (1.f-fx)*fy*S, fx*(1.f-fy)*S, fx*fy*S};
            int kidx[4] = {kx0*4+ky0, kx0*4+ky0+1, (kx0+1)*4+ky0, (kx0+1)*4+ky0+1};
            const float* xj = x + (size_t)sj * 16;
            float msg[16];
#pragma unroll
            for (int o = 0; o < 16; ++o) msg[o] = 0.f;
#pragma unroll
            for (int p = 0; p < 4; ++p) {
                const float* wk = Wl + kidx[p] * 320;
                for (int ii = 0; ii < 16; ++ii) {
                    float xw = xj[ii] * wgt[p];
#pragma unroll
                    for (int o = 0; o < 16; ++o)
                        msg[o] = fmaf(xw, wk[ii * 20 + o], msg[o]);
                }
            }
            float* tr = &tile[(di - nlo) * 16];
#pragma unroll
            for (int o = 0; o < 16; ++o) atomicAdd(tr + o, msg[o]);
        }
        __syncthreads();
    }

    const int base = bin * NPB * 16;
    const int lim = N_NODES * 16 - base;
    for (int j = tid; j < NPB * 16; j += GB_T)
        if (j < lim) out[base + j] = tile[j];
}

// ============== small-workspace fallbacks (unchanged) ==============
__global__ __launch_bounds__(256) void y_only_kernel(
    const float* __restrict__ x, const float* __restrict__ W,
    unsigned short* __restrict__ Y) {
    const int n = blockIdx.x * 256 + threadIdx.x;
    const int kbase = blockIdx.y * 4;
    if (n >= N_NODES) return;
    const float4* xv = (const float4*)(x + n * 16);
    float4 a = xv[0], b = xv[1], c = xv[2], d = xv[3];
    float xr[16] = {a.x,a.y,a.z,a.w, b.x,b.y,b.z,b.w,
                    c.x,c.y,c.z,c.w, d.x,d.y,d.z,d.w};
    float acc[4][16];
#pragma unroll
    for (int kk = 0; kk < 4; ++kk)
#pragma unroll
        for (int o = 0; o < 16; ++o) acc[kk][o] = 0.f;
#pragma unroll
    for (int i = 0; i < 16; ++i)
#pragma unroll
        for (int kk = 0; kk < 4; ++kk) {
            const float* wrow = W + ((kbase + kk) * 256 + i * 16);
#pragma unroll
            for (int o = 0; o < 16; ++o)
                acc[kk][o] = fmaf(xr[i], wrow[o], acc[kk][o]);
        }
    unsigned short* dst = Y + (size_t)n * 256 + kbase * 16;
#pragma unroll
    for (int kk = 0; kk < 4; ++kk) {
        unsigned pk[8];
#pragma unroll
        for (int q = 0; q < 8; ++q)
            pk[q] = (unsigned)f2bf(acc[kk][2*q]) | ((unsigned)f2bf(acc[kk][2*q+1]) << 16);
        uint4* p = (uint4*)(dst + kk * 16);
        p[0] = make_uint4(pk[0], pk[1], pk[2], pk[3]);
        p[1] = make_uint4(pk[4], pk[5], pk[6], pk[7]);
    }
}

__global__ __launch_bounds__(256) void edge_kernel(
    const float* __restrict__ edge_attr, const int* __restrict__ ei,
    const int* __restrict__ ej, const unsigned short* __restrict__ Y,
    float* __restrict__ out) {
    const int e = blockIdx.x * 256 + threadIdx.x;
    if (e >= N_EDGES) return;
    const int di = ei[e];
    const int sj = ej[e];
    const float2 ea = ((const float2*)edge_attr)[e];
    if (di == sj) return;
    float ux = fminf(fmaxf(ea.x, -1.f), 1.f);
    float uy = fminf(fmaxf(ea.y, -1.f), 1.f);
    float tx = (ux + 1.f) * 1.5f;
    float ty = (uy + 1.f) * 1.5f;
    int kx0 = min((int)tx, 2);
    int ky0 = min((int)ty, 2);
    float fx = tx - (float)kx0;
    float fy = ty - (float)ky0;
    const float S = 1.f / 128.f;
    float w00 = (1.f - fx) * (1.f - fy) * S;
    float w01 = (1.f - fx) * fy * S;
    float w10 = fx * (1.f - fy) * S;
    float w11 = fx * fy * S;
    const unsigned short* base = Y + (size_t)sj * 256 + (kx0 * 4 + ky0) * 16;
    const uint4* pA = (const uint4*)base;
    const uint4* pB = (const uint4*)(base + 64);
    uint4 a0 = pA[0], a1 = pA[1], a2 = pA[2], a3 = pA[3];
    uint4 b0 = pB[0], b1 = pB[1], b2 = pB[2], b3 = pB[3];
    unsigned ra0[8] = {a0.x,a0.y,a0.z,a0.w, a1.x,a1.y,a1.z,a1.w};
    unsigned ra1[8] = {a2.x,a2.y,a2.z,a2.w, a3.x,a3.y,a3.z,a3.w};
    unsigned rb0[8] = {b0.x,b0.y,b0.z,b0.w, b1.x,b1.y,b1.z,b1.w};
    unsigned rb1[8] = {b2.x,b2.y,b2.z,b2.w, b3.x,b3.y,b3.z,b3.w};
    float* o16 = out + (size_t)di * 16;
#pragma unroll
    for (int q = 0; q < 8; ++q) {
        float m0 = bflo(ra0[q]) * w00 + bflo(ra1[q]) * w01
                 + bflo(rb0[q]) * w10 + bflo(rb1[q]) * w11;
        float m1 = bfhi(ra0[q]) * w00 + bfhi(ra1[q]) * w01
                 + bfhi(rb0[q]) * w10 + bfhi(rb1[q]) * w11;
        atomicAdd(o16 + 2 * q, m0);
        atomicAdd(o16 + 2 * q + 1, m1);
    }
}

__global__ __launch_bounds__(256) void edge_direct(
    const float* __restrict__ x, const float* __restrict__ edge_attr,
    const float* __restrict__ W, const int* __restrict__ ei,
    const int* __restrict__ ej, float* __restrict__ out) {
    const int e = blockIdx.x * 256 + threadIdx.x;
    if (e >= N_EDGES) return;
    const int di = ei[e];
    const int sj = ej[e];
    const float2 ea = ((const float2*)edge_attr)[e];
    if (di == sj) return;
    float ux = fminf(fmaxf(ea.x, -1.f), 1.f);
    float uy = fminf(fmaxf(ea.y, -1.f), 1.f);
    float tx = (ux + 1.f) * 1.5f, ty = (uy + 1.f) * 1.5f;
    int kx0 = min((int)tx, 2), ky0 = min((int)ty, 2);
    float fx = tx - (float)kx0, fy = ty - (float)ky0;
    const float S = 1.f / 128.f;
    float wgt[4] = {(1.f-fx)*(1.f-fy)*S, (1.f-fx)*fy*S, fx*(1.f-fy)*S, fx*fy*S};
    int kidx[4] = {kx0*4+ky0, kx0*4+ky0+1, (kx0+1)*4+ky0, (kx0+1)*4+ky0+1};
    const float* xj = x + (size_t)sj * 16;
    float xr[16];
#pragma unroll
    for (int i = 0; i < 16; ++i) xr[i] = xj[i];
    float msg[16];
#pragma unroll
    for (int o = 0; o < 16; ++o) msg[o] = 0.f;
#pragma unroll
    for (int p = 0; p < 4; ++p) {
        const float* wk = W + kidx[p] * 256;
#pragma unroll
        for (int i = 0; i < 16; ++i) {
            float xw = xr[i] * wgt[p];
#pragma unroll
            for (int o = 0; o < 16; ++o)
                msg[o] = fmaf(xw, wk[i * 16 + o], msg[o]);
        }
    }
    float* o16 = out + (size_t)di * 16;
#pragma unroll
    for (int o = 0; o < 16; ++o) atomicAdd(o16 + o, msg[o]);
}

extern "C" void kernel_launch(void* const* d_in, const int* in_sizes, int n_in,
                              void* d_out, int out_size, void* d_ws, size_t ws_size,
                              hipStream_t stream) {
    const float* x         = (const float*)d_in[0];
    const float* edge_attr = (const float*)d_in[1];
    const float* W         = (const float*)d_in[2];
    const int*   ei        = (const int*)d_in[3];
    const int*   ej        = (const int*)d_in[4];
    float* out = (float*)d_out;
    char* ws = (char*)d_ws;

    // ---- bin-path workspace (16B aligned); cursor padded to 256B/bin ----
    const size_t oCur    = 0;                                   // NBINS*256 = 131,072
    const size_t oOvfCnt = oCur + (size_t)NBINS * CURSTRIDE * 4;// 16
    const size_t oOvf    = oOvfCnt + 16;                        // OVF_CAP*4 = 262,144
    const size_t oBkt    = oOvf + (size_t)OVF_CAP * 4;          // NBINS*CAPB*8 = 8,388,608
    const size_t total   = oBkt + (size_t)NBINS * CAPB * 8;     // ~8.8 MB

    if (ws_size >= total) {
        int*   cursor = (int*)(ws + oCur);
        int*   ovfCnt = (int*)(ws + oOvfCnt);
        int*   ovf    = (int*)(ws + oOvf);
        uint2* bkt    = (uint2*)(ws + oBkt);

        // R10: single cooperative dispatch (cursor zeroing fused in-kernel)
        void* params[] = {(void*)&cursor, (void*)&bkt, (void*)&x, (void*)&W,
                          (void*)&out, (void*)&ovfCnt, (void*)&ovf,
                          (void*)&edge_attr, (void*)&ei, (void*)&ej};
        hipError_t err = hipLaunchCooperativeKernel(
            fused_all, dim3(FB), dim3(FT), params, 0, stream);
        if (err == hipSuccess) return;
        (void)hipGetLastError();                    // clear, take fallback path

        // fallback: proven R9 3-dispatch path
        hipMemsetAsync(cursor, 0, (size_t)NBINS * CURSTRIDE * 4 + 16, stream);
        bucket_build<<<GA, 256, 0, stream>>>(
            edge_attr, ei, ej, cursor, bkt, ovfCnt, ovf);
        gather_conv<<<NBINS, GB_T, 0, stream>>>(
            cursor, bkt, x, W, out, ovfCnt, ovf, edge_attr, ei, ej);
        return;
    }

    const size_t yBytes = (size_t)N_NODES * 512;
    if (ws_size >= yBytes) {
        hipMemsetAsync(d_out, 0, (size_t)out_size * sizeof(float), stream);
        unsigned short* Y = (unsigned short*)d_ws;
        dim3 gA(NBY, 4);
        y_only_kernel<<<gA, 256, 0, stream>>>(x, W, Y);
        edge_kernel<<<HBLK, 256, 0, stream>>>(edge_attr, ei, ej, Y, out);
    } else {
        hipMemsetAsync(d_out, 0, (size_t)out_size * sizeof(float), stream);
        edge_direct<<<HBLK, 256, 0, stream>>>(x, edge_attr, W, ei, ej, out);
    }
}

// Round 13
// 202.594 us; speedup vs baseline: 1.9749x; 1.9749x over previous
//
#include <hip/hip_runtime.h>
#include <hip/hip_cooperative_groups.h>

namespace cg = cooperative_groups;

#define N_NODES 100000
#define N_EDGES 800000
#define NBY    ((N_NODES + 255) / 256)             // 391 (fallback path)
#define HBLK   ((N_EDGES + 255) / 256)             // 3125 (fallback path)
#define OVF_CAP 65536
#define GA     250                                 // fallback phase-A blocks
#define CHUNK  3200                                // fallback edges/block
#define NBINS  512
#define NPB    196                                 // nodes per bin (512*196 = 100352)
#define CAPB   2048                                // slots/bin (mean 1562, sigma ~40)
#define GB_T   1024                                // gather block threads
#define CURSTRIDE 64                               // ints; 256B per cursor line
// R13 fused config: 256 blocks x 1024 thr = 1 block/CU (co-residency easy).
// R12 LESSON: launch_bounds(1024,8) forced a 32-VGPR budget -> t[16][4]+po[16]
// spilled to scratch (453MB WRITE_SIZE, 301us). (1024,4) -> 128-VGPR cap.
#define FB     256
#define FT     1024
#define PACHUNK 3125                               // 256*3125 = 800000 exactly
// record: .x = sj*512 + (kx0*4+ky0)*32 ; .y = fx12 | fy12<<12 | local<<24

__device__ __forceinline__ unsigned short f2bf(float f) {
    union { float f; unsigned u; } v; v.f = f;
    unsigned u = v.u;
    return (unsigned short)((u + 0x7FFFu + ((u >> 16) & 1u)) >> 16);  // RNE
}
__device__ __forceinline__ float bflo(unsigned u) {
    union { unsigned u; float f; } v; v.u = u << 16; return v.f;
}
__device__ __forceinline__ float bfhi(unsigned u) {
    union { unsigned u; float f; } v; v.u = u & 0xFFFF0000u; return v.f;
}

// ================= R13: single cooperative kernel, spill-free =================
// {zero cursors + phase A pass1} -> grid.sync -> {pass2+pass3} -> grid.sync
// -> phase B loop over bins {b, b+256} (R9-verified per-bin logic).
__global__ __launch_bounds__(FT, 4) void fused_all(
    int* __restrict__ cursor, uint2* __restrict__ bkt,
    const float* __restrict__ x, const float* __restrict__ W,
    float* __restrict__ out, int* __restrict__ ovfCnt, int* __restrict__ ovf,
    const float* __restrict__ edge_attr, const int* __restrict__ ei,
    const int* __restrict__ ej) {
    cg::grid_group grid = cg::this_grid();
    const int b = blockIdx.x;
    const int tid = threadIdx.x;

    __shared__ __align__(16) char SM[52576];
    // phase B layout
    uint2* sorted = (uint2*)SM;                    // 16384 B
    uint2* rawS   = (uint2*)(SM + 16384);          // stage-1 record staging (16384)
    float* Wl     = (float*)(SM + 16384);          // padded W [16][16][20] (20480)
    float* tile   = (float*)(SM + 36864);          // 12544 B
    int*   h      = (int*)(SM + 49408);            // 784 B
    int*   st     = (int*)(SM + 50192);
    int*   en     = (int*)(SM + 50976);
    int*   cur    = (int*)(SM + 51760);
    int*   wsum   = (int*)(SM + 52544);
    // phase A aliases (dead before phase B writes these regions)
    unsigned* rawA = (unsigned*)SM;                // 12500 B
    unsigned* rawB = (unsigned*)(SM + 12512);      // 12500 B
    short*  rawBin = (short*)(SM + 25024);         // 6250 B
    int*    hist   = (int*)(SM + 31280);           // 2048 B

    // zero this block's two cursor lines + ovfCnt (device-scope; post-sync1)
    if (tid == 0) {
        atomicExch(&cursor[b * CURSTRIDE], 0);
        atomicExch(&cursor[(b + FB) * CURSTRIDE], 0);
        if (b == 0) atomicExch(ovfCnt, 0);
    }

    // ---- phase A pass 1: all 256 blocks, block-local LDS only ----
    {
        if (tid < NBINS) hist[tid] = 0;
        __syncthreads();
        const int base = b * PACHUNK;
        for (int i = 0; i < PACHUNK; i += FT) {
            const int j = i + tid;
            if (j >= PACHUNK) continue;            // 3125 % 1024 != 0 guard
            const int e = base + j;
            short binS = -1;
            const int di = ei[e];
            const int sj = ej[e];
            if (di != sj) {                        // centerIgnore
                const float2 ea = ((const float2*)edge_attr)[e];
                float ux = fminf(fmaxf(ea.x, -1.f), 1.f);
                float uy = fminf(fmaxf(ea.y, -1.f), 1.f);
                float tx = (ux + 1.f) * 1.5f;
                float ty = (uy + 1.f) * 1.5f;
                int kx0 = min((int)tx, 2);
                int ky0 = min((int)ty, 2);
                float fx = tx - (float)kx0;
                float fy = ty - (float)ky0;
                unsigned fx12 = (unsigned)(fx * 4095.f + 0.5f);
                unsigned fy12 = (unsigned)(fy * 4095.f + 0.5f);
                const int bn = di / NPB;
                const unsigned local = (unsigned)(di - bn * NPB);   // < 196
                rawA[j] = (unsigned)(sj * 512 + (kx0 * 4 + ky0) * 32);
                rawB[j] = fx12 | (fy12 << 12) | (local << 24);
                binS = (short)bn;
                atomicAdd(&hist[bn], 1);
            }
            rawBin[j] = binS;
        }
    }

    grid.sync();   // all cursors zeroed; all pass-1 LDS records built

    {
        // pass 2: one returning global atomic per non-empty (block,bin)
        if (tid < NBINS) {
            const int c = hist[tid];
            int g = 0;
            if (c > 0) g = atomicAdd(&cursor[tid * CURSTRIDE], c);
            hist[tid] = tid * CAPB + g;
        }
        __syncthreads();
        // pass 3: replay from LDS, slot via LDS atomic, 8B global store
        const int base = b * PACHUNK;
        for (int i = 0; i < PACHUNK; i += FT) {
            const int j = i + tid;
            if (j >= PACHUNK) continue;
            const int bn = rawBin[j];
            if (bn < 0) continue;
            const int s = atomicAdd(&hist[bn], 1);
            if (s - bn * CAPB < CAPB) {
                bkt[s] = make_uint2(rawA[j], rawB[j]);
            } else {
                const int o = atomicAdd(ovfCnt, 1);
                if (o < OVF_CAP) ovf[o] = base + j;
            }
        }
    }

    grid.sync();   // all bkt/ovf/cursor writes visible (release/acquire fences)

    // ============ phase B: two bins per block (R9-verified logic) ============
    const float U = 1.f / 4095.f;
    const float S = 1.f / 128.f;                   // OUTPUT_SCALING
    const int lane = tid & 63;
    const int wid  = tid >> 6;

    for (int bin = b; bin < NBINS; bin += FB) {
        // per-bin LDS lifecycle starts: zero h, barrier
        for (int j = tid; j < NPB; j += FT) h[j] = 0;
        __syncthreads();

        const int cnt = min(cursor[bin * CURSTRIDE], CAPB);
        const int pad = (cnt + NPB <= CAPB) ? 1 : 0;   // stagger only if slots allow
        const uint2* rb = bkt + (size_t)bin * CAPB;

        // stage 1: single global read of records -> LDS rawS[], histogram
        for (int p = tid; p < cnt; p += FT) {
            uint2 r = rb[p];
            rawS[p] = r;
            atomicAdd(&h[r.y >> 24], 1);
        }
        __syncthreads();

        // stage 2: wave64 shfl_up scan + 4-wave combine (2 barriers)
        int c0 = 0, v = 0;
        if (tid < 256) {                           // waves 0..3 cover NPB=196
            c0 = (tid < NPB) ? h[tid] : 0;
            v = c0;
#pragma unroll
            for (int off = 1; off < 64; off <<= 1) {
                int u = __shfl_up(v, off);
                if (lane >= off) v += u;
            }
            if (lane == 63) wsum[wid] = v;
        }
        __syncthreads();
        if (tid < NPB) {
            int pfx = 0;
#pragma unroll
            for (int w = 0; w < 4; ++w)
                if (w < wid) pfx += wsum[w];
            const int incl = v + pfx;
            const int sh = tid * pad;              // bank stagger (+node)
            en[tid]  = incl + sh;
            st[tid]  = incl - c0 + sh;
            cur[tid] = incl - c0 + sh;
        }
        __syncthreads();

        // stage 3: scatter into (staggered) sorted order -- LDS -> LDS
        for (int p = tid; p < cnt; p += FT) {
            uint2 r = rawS[p];
            int pos = atomicAdd(&cur[r.y >> 24], 1);
            sorted[pos] = r;
        }
        __syncthreads();

        // stage W: rawS dead; stage W into padded Wl (same buffer)
        {
            float4 w = ((const float4*)W)[tid];
            const int k = tid >> 6, i2 = (tid >> 2) & 15, o4 = tid & 3;
            *(float4*)&Wl[k * 320 + i2 * 20 + o4 * 4] = w;
        }
        __syncthreads();

        // stage 4: input-space accumulation, 4 threads/node (784 active)
        if (tid < 4 * NPB) {
            const int node = tid >> 2;
            const int q4 = tid & 3;
            float t[16][4];
#pragma unroll
            for (int k = 0; k < 16; ++k)
#pragma unroll
                for (int i = 0; i < 4; ++i) t[k][i] = 0.f;

            const int lo = st[node], hi2 = en[node];
            uint2 m = make_uint2(0u, 0u);
            float4 xv = make_float4(0.f, 0.f, 0.f, 0.f);
            if (lo < hi2) {
                m = sorted[lo];
                xv = ((const float4*)x)[(m.x >> 9) * 4 + q4];
            }
            for (int idx = lo; idx < hi2; ++idx) {
                const uint2 mc = m;
                const float4 xc = xv;
                if (idx + 1 < hi2) {               // prefetch next (hides L2 latency)
                    m = sorted[idx + 1];
                    xv = ((const float4*)x)[(m.x >> 9) * 4 + q4];
                }
                const unsigned koff = (mc.x >> 5) & 15u;
                const int kx0 = (int)(koff >> 2);
                const int ky0 = (int)(koff & 3u);
                const float fx = (float)(mc.y & 0xFFFu) * U;
                const float fy = (float)((mc.y >> 12) & 0xFFFu) * U;
                float wx[4], wy[4];
#pragma unroll
                for (int a = 0; a < 4; ++a) {
                    wx[a] = (a == kx0) ? (1.f - fx) : ((a == kx0 + 1) ? fx : 0.f);
                    wy[a] = (a == ky0) ? (1.f - fy) : ((a == ky0 + 1) ? fy : 0.f);
                }
                const float xr[4] = {xc.x, xc.y, xc.z, xc.w};
#pragma unroll
                for (int kx = 0; kx < 4; ++kx)
#pragma unroll
                    for (int ky = 0; ky < 4; ++ky) {
                        const float w = wx[kx] * wy[ky];
#pragma unroll
                        for (int i = 0; i < 4; ++i)
                            t[kx * 4 + ky][i] = fmaf(w, xr[i], t[kx * 4 + ky][i]);
                    }
            }

            // epilogue: contract t with Wl (padded stride 20 -> 2-way max)
            float po[16];
#pragma unroll
            for (int o = 0; o < 16; ++o) po[o] = 0.f;
#pragma unroll
            for (int k = 0; k < 16; ++k)
#pragma unroll
                for (int il = 0; il < 4; ++il) {
                    const float tv = t[k][il];
                    const float4* wr = (const float4*)&Wl[k * 320 + (q4 * 4 + il) * 20];
                    const float4 w0 = wr[0], w1 = wr[1], w2 = wr[2], w3 = wr[3];
                    po[0]  = fmaf(tv, w0.x, po[0]);  po[1]  = fmaf(tv, w0.y, po[1]);
                    po[2]  = fmaf(tv, w0.z, po[2]);  po[3]  = fmaf(tv, w0.w, po[3]);
                    po[4]  = fmaf(tv, w1.x, po[4]);  po[5]  = fmaf(tv, w1.y, po[5]);
                    po[6]  = fmaf(tv, w1.z, po[6]);  po[7]  = fmaf(tv, w1.w, po[7]);
                    po[8]  = fmaf(tv, w2.x, po[8]);  po[9]  = fmaf(tv, w2.y, po[9]);
                    po[10] = fmaf(tv, w2.z, po[10]); po[11] = fmaf(tv, w2.w, po[11]);
                    po[12] = fmaf(tv, w3.x, po[12]); po[13] = fmaf(tv, w3.y, po[13]);
                    po[14] = fmaf(tv, w3.z, po[14]); po[15] = fmaf(tv, w3.w, po[15]);
                }

            // reduce across the 4-lane group (lane-aligned, all active)
#pragma unroll
            for (int o = 0; o < 16; ++o) {
                po[o] += __shfl_xor(po[o], 1);
                po[o] += __shfl_xor(po[o], 2);
            }
            if (q4 == 0) {
                float* tr = &tile[node * 16];
#pragma unroll
                for (int o = 0; o < 16; ++o) tr[o] = po[o] * S;
            }
        }
        __syncthreads();

        // stage 4b: fused overflow fix-up (ovfCnt ~always 0 -> one read, skip)
        const int mv = min(*ovfCnt, OVF_CAP);
        if (mv > 0) {
            const int nlo = bin * NPB;
            const int nhi = min(nlo + NPB, N_NODES);
            for (int i = tid; i < mv; i += FT) {
                const int e = ovf[i];
                const int di = ei[e];
                if (di < nlo || di >= nhi) continue;
                const int sj = ej[e];
                const float2 ea = ((const float2*)edge_attr)[e];
                float ux = fminf(fmaxf(ea.x, -1.f), 1.f);
                float uy = fminf(fmaxf(ea.y, -1.f), 1.f);
                float tx = (ux + 1.f) * 1.5f, ty = (uy + 1.f) * 1.5f;
                int kx0 = min((int)tx, 2), ky0 = min((int)ty, 2);
                float fx = tx - (float)kx0, fy = ty - (float)ky0;
                float wgt[4] = {(1.f-fx)*(1.f-fy)*S, (1.f-fx)*fy*S, fx*(1.f-fy)*S, fx*fy*S};
                int kidx[4] = {kx0*4+ky0, kx0*4+ky0+1, (kx0+1)*4+ky0, (kx0+1)*4+ky0+1};
                const float* xj = x + (size_t)sj * 16;
                float msg[16];
#pragma unroll
                for (int o = 0; o < 16; ++o) msg[o] = 0.f;
#pragma unroll
                for (int p = 0; p < 4; ++p) {
                    const float* wk = Wl + kidx[p] * 320;     // padded stride
                    for (int ii = 0; ii < 16; ++ii) {
                        float xw = xj[ii] * wgt[p];
#pragma unroll
                        for (int o = 0; o < 16; ++o)
                            msg[o] = fmaf(xw, wk[ii * 20 + o], msg[o]);
                    }
                }
                float* tr = &tile[(di - nlo) * 16];
#pragma unroll
                for (int o = 0; o < 16; ++o) atomicAdd(tr + o, msg[o]);
            }
            __syncthreads();
        }

        // stage 5: coalesced block store (bins own disjoint node ranges)
        const int base2 = bin * NPB * 16;
        const int lim = N_NODES * 16 - base2;
        for (int j = tid; j < NPB * 16; j += FT)
            if (j < lim) out[base2 + j] = tile[j];
    }
}

// ================= fallback: R9 3-dispatch path (unchanged) =================
__global__ __launch_bounds__(256) void bucket_build(
    const float* __restrict__ edge_attr,
    const int* __restrict__ ei, const int* __restrict__ ej,
    int* __restrict__ cursor, uint2* __restrict__ bkt,
    int* __restrict__ ovfCnt, int* __restrict__ ovf) {
    const int b = blockIdx.x;
    __shared__ int hist[NBINS];
    __shared__ unsigned rawA[CHUNK];
    __shared__ unsigned rawB[CHUNK];
    __shared__ short rawBin[CHUNK];
    const int tid = threadIdx.x;
    for (int k = tid; k < NBINS; k += 256) hist[k] = 0;
    __syncthreads();
    const int base = b * CHUNK;
    for (int i = 0; i < CHUNK; i += 256) {
        const int j = i + tid;
        if (j >= CHUNK) continue;
        const int e = base + j;
        short binS = -1;
        if (e < N_EDGES) {
            const int di = ei[e];
            const int sj = ej[e];
            if (di != sj) {
                const float2 ea = ((const float2*)edge_attr)[e];
                float ux = fminf(fmaxf(ea.x, -1.f), 1.f);
                float uy = fminf(fmaxf(ea.y, -1.f), 1.f);
                float tx = (ux + 1.f) * 1.5f;
                float ty = (uy + 1.f) * 1.5f;
                int kx0 = min((int)tx, 2);
                int ky0 = min((int)ty, 2);
                float fx = tx - (float)kx0;
                float fy = ty - (float)ky0;
                unsigned fx12 = (unsigned)(fx * 4095.f + 0.5f);
                unsigned fy12 = (unsigned)(fy * 4095.f + 0.5f);
                const int bin = di / NPB;
                const unsigned local = (unsigned)(di - bin * NPB);
                rawA[j] = (unsigned)(sj * 512 + (kx0 * 4 + ky0) * 32);
                rawB[j] = fx12 | (fy12 << 12) | (local << 24);
                binS = (short)bin;
                atomicAdd(&hist[bin], 1);
            }
        }
        rawBin[j] = binS;
    }
    __syncthreads();
    for (int k = tid; k < NBINS; k += 256) {
        const int c = hist[k];
        int g = 0;
        if (c > 0) g = atomicAdd(&cursor[k * CURSTRIDE], c);
        hist[k] = k * CAPB + g;
    }
    __syncthreads();
    for (int i = 0; i < CHUNK; i += 256) {
        const int j = i + tid;
        if (j >= CHUNK) continue;
        const int bin = rawBin[j];
        if (bin < 0) continue;
        const int s = atomicAdd(&hist[bin], 1);
        if (s - bin * CAPB < CAPB) {
            bkt[s] = make_uint2(rawA[j], rawB[j]);
        } else {
            const int o = atomicAdd(ovfCnt, 1);
            if (o < OVF_CAP) ovf[o] = base + j;
        }
    }
}

__global__ __launch_bounds__(GB_T) void gather_conv(
    const int* __restrict__ cursor, const uint2* __restrict__ bkt,
    const float* __restrict__ x, const float* __restrict__ W,
    float* __restrict__ out,
    const int* __restrict__ ovfCnt, const int* __restrict__ ovf,
    const float* __restrict__ edge_attr, const int* __restrict__ ei,
    const int* __restrict__ ej) {
    const int bin = blockIdx.x;
    const int tid = threadIdx.x;
    __shared__ uint2 sorted[CAPB];
    __shared__ __align__(16) char u_buf[20480];
    __shared__ int h[NPB];
    __shared__ int st[NPB], en[NPB], cur[NPB];
    __shared__ int wsum[4];
    __shared__ float tile[NPB * 16];
    uint2* raw = (uint2*)u_buf;
    float* Wl  = (float*)u_buf;

    for (int j = tid; j < NPB; j += GB_T) h[j] = 0;
    __syncthreads();

    const int cnt = min(cursor[bin * CURSTRIDE], CAPB);
    const int pad = (cnt + NPB <= CAPB) ? 1 : 0;
    const uint2* rb = bkt + (size_t)bin * CAPB;

    for (int p = tid; p < cnt; p += GB_T) {
        uint2 r = rb[p];
        raw[p] = r;
        atomicAdd(&h[r.y >> 24], 1);
    }
    __syncthreads();

    const int lane = tid & 63;
    const int wid  = tid >> 6;
    int c0 = 0, v = 0;
    if (tid < 256) {
        c0 = (tid < NPB) ? h[tid] : 0;
        v = c0;
#pragma unroll
        for (int off = 1; off < 64; off <<= 1) {
            int u = __shfl_up(v, off);
            if (lane >= off) v += u;
        }
        if (lane == 63) wsum[wid] = v;
    }
    __syncthreads();
    if (tid < NPB) {
        int pfx = 0;
#pragma unroll
        for (int w = 0; w < 4; ++w)
            if (w < wid) pfx += wsum[w];
        const int incl = v + pfx;
        const int sh = tid * pad;
        en[tid]  = incl + sh;
        st[tid]  = incl - c0 + sh;
        cur[tid] = incl - c0 + sh;
    }
    __syncthreads();

    for (int p = tid; p < cnt; p += GB_T) {
        uint2 r = raw[p];
        int pos = atomicAdd(&cur[r.y >> 24], 1);
        sorted[pos] = r;
    }
    __syncthreads();

    {
        float4 w = ((const float4*)W)[tid];
        const int k = tid >> 6, i = (tid >> 2) & 15, o4 = tid & 3;
        *(float4*)&Wl[k * 320 + i * 20 + o4 * 4] = w;
    }
    __syncthreads();

    const float U = 1.f / 4095.f;
    const float S = 1.f / 128.f;
    if (tid < 4 * NPB) {
        const int node = tid >> 2;
        const int q4 = tid & 3;
        float t[16][4];
#pragma unroll
        for (int k = 0; k < 16; ++k)
#pragma unroll
            for (int i = 0; i < 4; ++i) t[k][i] = 0.f;

        const int lo = st[node], hi2 = en[node];
        uint2 m = make_uint2(0u, 0u);
        float4 xv = make_float4(0.f, 0.f, 0.f, 0.f);
        if (lo < hi2) {
            m = sorted[lo];
            xv = ((const float4*)x)[(m.x >> 9) * 4 + q4];
        }
        for (int idx = lo; idx < hi2; ++idx) {
            const uint2 mc = m;
            const float4 xc = xv;
            if (idx + 1 < hi2) {
                m = sorted[idx + 1];
                xv = ((const float4*)x)[(m.x >> 9) * 4 + q4];
            }
            const unsigned koff = (mc.x >> 5) & 15u;
            const int kx0 = (int)(koff >> 2);
            const int ky0 = (int)(koff & 3u);
            const float fx = (float)(mc.y & 0xFFFu) * U;
            const float fy = (float)((mc.y >> 12) & 0xFFFu) * U;
            float wx[4], wy[4];
#pragma unroll
            for (int a = 0; a < 4; ++a) {
                wx[a] = (a == kx0) ? (1.f - fx) : ((a == kx0 + 1) ? fx : 0.f);
                wy[a] = (a == ky0) ? (1.f - fy) : ((a == ky0 + 1) ? fy : 0.f);
            }
            const float xr[4] = {xc.x, xc.y, xc.z, xc.w};
#pragma unroll
            for (int kx = 0; kx < 4; ++kx)
#pragma unroll
                for (int ky = 0; ky < 4; ++ky) {
                    const float w = wx[kx] * wy[ky];
#pragma unroll
                    for (int i = 0; i < 4; ++i)
                        t[kx * 4 + ky][i] = fmaf(w, xr[i], t[kx * 4 + ky][i]);
                }
        }

        float po[16];
#pragma unroll
        for (int o = 0; o < 16; ++o) po[o] = 0.f;
#pragma unroll
        for (int k = 0; k < 16; ++k)
#pragma unroll
            for (int il = 0; il < 4; ++il) {
                const float tv = t[k][il];
                const float4* wr = (const float4*)&Wl[k * 320 + (q4 * 4 + il) * 20];
                const float4 w0 = wr[0], w1 = wr[1], w2 = wr[2], w3 = wr[3];
                po[0]  = fmaf(tv, w0.x, po[0]);  po[1]  = fmaf(tv, w0.y, po[1]);
                po[2]  = fmaf(tv, w0.z, po[2]);  po[3]  = fmaf(tv, w0.w, po[3]);
                po[4]  = fmaf(tv, w1.x, po[4]);  po[5]  = fmaf(tv, w1.y, po[5]);
                po[6]  = fmaf(tv, w1.z, po[6]);  po[7]  = fmaf(tv, w1.w, po[7]);
                po[8]  = fmaf(tv, w2.x, po[8]);  po[9]  = fmaf(tv, w2.y, po[9]);
                po[10] = fmaf(tv, w2.z, po[10]); po[11] = fmaf(tv, w2.w, po[11]);
                po[12] = fmaf(tv, w3.x, po[12]); po[13] = fmaf(tv, w3.y, po[13]);
                po[14] = fmaf(tv, w3.z, po[14]); po[15] = fmaf(tv, w3.w, po[15]);
            }

#pragma unroll
        for (int o = 0; o < 16; ++o) {
            po[o] += __shfl_xor(po[o], 1);
            po[o] += __shfl_xor(po[o], 2);
        }
        if (q4 == 0) {
            float* tr = &tile[node * 16];
#pragma unroll
            for (int o = 0; o < 16; ++o) tr[o] = po[o] * S;
        }
    }
    __syncthreads();

    const int m = min(*ovfCnt, OVF_CAP);
    if (m > 0) {
        const int nlo = bin * NPB;
        const int nhi = min(nlo + NPB, N_NODES);
        for (int i = tid; i < m; i += GB_T) {
            const int e = ovf[i];
            const int di = ei[e];
            if (di < nlo || di >= nhi) continue;
            const int sj = ej[e];
            const float2 ea = ((const float2*)edge_attr)[e];
            float ux = fminf(fmaxf(ea.x, -1.f), 1.f);
            float uy = fminf(fmaxf(ea.y, -1.f), 1.f);
            float tx = (ux + 1.f) * 1.5f, ty = (uy + 1.f) * 1.5f;
            int kx0 = min((int)tx, 2), ky0 = min((int)ty, 2);
            float fx = tx - (float)kx0, fy = ty - (float)ky0;
            float wgt[4] = {(1.f-fx)*(1.f-fy)*S, (1.f-fx)*fy*S, fx*(1.f-fy)*S, fx*fy*S};
            int kidx[4] = {kx0*4+ky0, kx0*4+ky0+1, (kx0+1)*4+ky0, (kx0+1)*4+ky0+1};
            const float* xj = x + (size_t)sj * 16;
            float msg[16];
#pragma unroll
            for (int o = 0; o < 16; ++o) msg[o] = 0.f;
#pragma unroll
            for (int p = 0; p < 4; ++p) {
                const float* wk = Wl + kidx[p] * 320;
                for (int ii = 0; ii < 16; ++ii) {
                    float xw = xj[ii] * wgt[p];
#pragma unroll
                    for (int o = 0; o < 16; ++o)
                        msg[o] = fmaf(xw, wk[ii * 20 + o], msg[o]);
                }
            }
            float* tr = &tile[(di - nlo) * 16];
#pragma unroll
            for (int o = 0; o < 16; ++o) atomicAdd(tr + o, msg[o]);
        }
        __syncthreads();
    }

    const int base = bin * NPB * 16;
    const int lim = N_NODES * 16 - base;
    for (int j = tid; j < NPB * 16; j += GB_T)
        if (j < lim) out[base + j] = tile[j];
}

// ============== small-workspace fallbacks (unchanged) ==============
__global__ __launch_bounds__(256) void y_only_kernel(
    const float* __restrict__ x, const float* __restrict__ W,
    unsigned short* __restrict__ Y) {
    const int n = blockIdx.x * 256 + threadIdx.x;
    const int kbase = blockIdx.y * 4;
    if (n >= N_NODES) return;
    const float4* xv = (const float4*)(x + n * 16);
    float4 a = xv[0], b = xv[1], c = xv[2], d = xv[3];
    float xr[16] = {a.x,a.y,a.z,a.w, b.x,b.y,b.z,b.w,
                    c.x,c.y,c.z,c.w, d.x,d.y,d.z,d.w};
    float acc[4][16];
#pragma unroll
    for (int kk = 0; kk < 4; ++kk)
#pragma unroll
        for (int o = 0; o < 16; ++o) acc[kk][o] = 0.f;
#pragma unroll
    for (int i = 0; i < 16; ++i)
#pragma unroll
        for (int kk = 0; kk < 4; ++kk) {
            const float* wrow = W + ((kbase + kk) * 256 + i * 16);
#pragma unroll
            for (int o = 0; o < 16; ++o)
                acc[kk][o] = fmaf(xr[i], wrow[o], acc[kk][o]);
        }
    unsigned short* dst = Y + (size_t)n * 256 + kbase * 16;
#pragma unroll
    for (int kk = 0; kk < 4; ++kk) {
        unsigned pk[8];
#pragma unroll
        for (int q = 0; q < 8; ++q)
            pk[q] = (unsigned)f2bf(acc[kk][2*q]) | ((unsigned)f2bf(acc[kk][2*q+1]) << 16);
        uint4* p = (uint4*)(dst + kk * 16);
        p[0] = make_uint4(pk[0], pk[1], pk[2], pk[3]);
        p[1] = make_uint4(pk[4], pk[5], pk[6], pk[7]);
    }
}

__global__ __launch_bounds__(256) void edge_kernel(
    const float* __restrict__ edge_attr, const int* __restrict__ ei,
    const int* __restrict__ ej, const unsigned short* __restrict__ Y,
    float* __restrict__ out) {
    const int e = blockIdx.x * 256 + threadIdx.x;
    if (e >= N_EDGES) return;
    const int di = ei[e];
    const int sj = ej[e];
    const float2 ea = ((const float2*)edge_attr)[e];
    if (di == sj) return;
    float ux = fminf(fmaxf(ea.x, -1.f), 1.f);
    float uy = fminf(fmaxf(ea.y, -1.f), 1.f);
    float tx = (ux + 1.f) * 1.5f;
    float ty = (uy + 1.f) * 1.5f;
    int kx0 = min((int)tx, 2);
    int ky0 = min((int)ty, 2);
    float fx = tx - (float)kx0;
    float fy = ty - (float)ky0;
    const float S = 1.f / 128.f;
    float w00 = (1.f - fx) * (1.f - fy) * S;
    float w01 = (1.f - fx) * fy * S;
    float w10 = fx * (1.f - fy) * S;
    float w11 = fx * fy * S;
    const unsigned short* base = Y + (size_t)sj * 256 + (kx0 * 4 + ky0) * 16;
    const uint4* pA = (const uint4*)base;
    const uint4* pB = (const uint4*)(base + 64);
    uint4 a0 = pA[0], a1 = pA[1], a2 = pA[2], a3 = pA[3];
    uint4 b0 = pB[0], b1 = pB[1], b2 = pB[2], b3 = pB[3];
    unsigned ra0[8] = {a0.x,a0.y,a0.z,a0.w, a1.x,a1.y,a1.z,a1.w};
    unsigned ra1[8] = {a2.x,a2.y,a2.z,a2.w, a3.x,a3.y,a3.z,a3.w};
    unsigned rb0[8] = {b0.x,b0.y,b0.z,b0.w, b1.x,b1.y,b1.z,b1.w};
    unsigned rb1[8] = {b2.x,b2.y,b2.z,b2.w, b3.x,b3.y,b3.z,b3.w};
    float* o16 = out + (size_t)di * 16;
#pragma unroll
    for (int q = 0; q < 8; ++q) {
        float m0 = bflo(ra0[q]) * w00 + bflo(ra1[q]) * w01
                 + bflo(rb0[q]) * w10 + bflo(rb1[q]) * w11;
        float m1 = bfhi(ra0[q]) * w00 + bfhi(ra1[q]) * w01
                 + bfhi(rb0[q]) * w10 + bfhi(rb1[q]) * w11;
        atomicAdd(o16 + 2 * q, m0);
        atomicAdd(o16 + 2 * q + 1, m1);
    }
}

__global__ __launch_bounds__(256) void edge_direct(
    const float* __restrict__ x, const float* __restrict__ edge_attr,
    const float* __restrict__ W, const int* __restrict__ ei,
    const int* __restrict__ ej, float* __restrict__ out) {
    const int e = blockIdx.x * 256 + threadIdx.x;
    if (e >= N_EDGES) return;
    const int di = ei[e];
    const int sj = ej[e];
    const float2 ea = ((const float2*)edge_attr)[e];
    if (di == sj) return;
    float ux = fminf(fmaxf(ea.x, -1.f), 1.f);
    float uy = fminf(fmaxf(ea.y, -1.f), 1.f);
    float tx = (ux + 1.f) * 1.5f, ty = (uy + 1.f) * 1.5f;
    int kx0 = min((int)tx, 2), ky0 = min((int)ty, 2);
    float fx = tx - (float)kx0, fy = ty - (float)ky0;
    const float S = 1.f / 128.f;
    float wgt[4] = {(1.f-fx)*(1.f-fy)*S, (1.f-fx)*fy*S, fx*(1.f-fy)*S, fx*fy*S};
    int kidx[4] = {kx0*4+ky0, kx0*4+ky0+1, (kx0+1)*4+ky0, (kx0+1)*4+ky0+1};
    const float* xj = x + (size_t)sj * 16;
    float xr[16];
#pragma unroll
    for (int i = 0; i < 16; ++i) xr[i] = xj[i];
    float msg[16];
#pragma unroll
    for (int o = 0; o < 16; ++o) msg[o] = 0.f;
#pragma unroll
    for (int p = 0; p < 4; ++p) {
        const float* wk = W + kidx[p] * 256;
#pragma unroll
        for (int i = 0; i < 16; ++i) {
            float xw = xr[i] * wgt[p];
#pragma unroll
            for (int o = 0; o < 16; ++o)
                msg[o] = fmaf(xw, wk[i * 16 + o], msg[o]);
        }
    }
    float* o16 = out + (size_t)di * 16;
#pragma unroll
    for (int o = 0; o < 16; ++o) atomicAdd(o16 + o, msg[o]);
}

extern "C" void kernel_launch(void* const* d_in, const int* in_sizes, int n_in,
                              void* d_out, int out_size, void* d_ws, size_t ws_size,
                              hipStream_t stream) {
    const float* x         = (const float*)d_in[0];
    const float* edge_attr = (const float*)d_in[1];
    const float* W         = (const float*)d_in[2];
    const int*   ei        = (const int*)d_in[3];
    const int*   ej        = (const int*)d_in[4];
    float* out = (float*)d_out;
    char* ws = (char*)d_ws;

    // ---- bin-path workspace (16B aligned); cursor padded to 256B/bin ----
    const size_t oCur    = 0;                                   // NBINS*256 = 131,072
    const size_t oOvfCnt = oCur + (size_t)NBINS * CURSTRIDE * 4;// 16
    const size_t oOvf    = oOvfCnt + 16;                        // OVF_CAP*4 = 262,144
    const size_t oBkt    = oOvf + (size_t)OVF_CAP * 4;          // NBINS*CAPB*8 = 8,388,608
    const size_t total   = oBkt + (size_t)NBINS * CAPB * 8;     // ~8.8 MB

    if (ws_size >= total) {
        int*   cursor = (int*)(ws + oCur);
        int*   ovfCnt = (int*)(ws + oOvfCnt);
        int*   ovf    = (int*)(ws + oOvf);
        uint2* bkt    = (uint2*)(ws + oBkt);

        // R13: single cooperative dispatch, 256 blocks (1/CU), 128-VGPR budget
        void* params[] = {(void*)&cursor, (void*)&bkt, (void*)&x, (void*)&W,
                          (void*)&out, (void*)&ovfCnt, (void*)&ovf,
                          (void*)&edge_attr, (void*)&ei, (void*)&ej};
        hipError_t err = hipLaunchCooperativeKernel(
            fused_all, dim3(FB), dim3(FT), params, 0, stream);
        if (err == hipSuccess) return;
        (void)hipGetLastError();                    // clear, take fallback path

        // fallback: proven R9 3-dispatch path
        hipMemsetAsync(cursor, 0, (size_t)NBINS * CURSTRIDE * 4 + 16, stream);
        bucket_build<<<GA, 256, 0, stream>>>(
            edge_attr, ei, ej, cursor, bkt, ovfCnt, ovf);
        gather_conv<<<NBINS, GB_T, 0, stream>>>(
            cursor, bkt, x, W, out, ovfCnt, ovf, edge_attr, ei, ej);
        return;
    }

    const size_t yBytes = (size_t)N_NODES * 512;
    if (ws_size >= yBytes) {
        hipMemsetAsync(d_out, 0, (size_t)out_size * sizeof(float), stream);
        unsigned short* Y = (unsigned short*)d_ws;
        dim3 gA(NBY, 4);
        y_only_kernel<<<gA, 256, 0, stream>>>(x, W, Y);
        edge_kernel<<<HBLK, 256, 0, stream>>>(edge_attr, ei, ej, Y, out);
    } else {
        hipMemsetAsync(d_out, 0, (size_t)out_size * sizeof(float), stream);
        edge_direct<<<HBLK, 256, 0, stream>>>(x, edge_attr, W, ei, ej, out);
    }
}

// Round 16
// 129.849 us; speedup vs baseline: 3.0813x; 1.5602x over previous
//
#include <hip/hip_runtime.h>

#define N_NODES 100000
#define N_EDGES 800000
#define NBY    ((N_NODES + 255) / 256)             // 391 (fallback path)
#define HBLK   ((N_EDGES + 255) / 256)             // 3125 (fallback path)
#define OVF_CAP 65536
#define GA     500                                 // phase-A blocks (R14: 1024-thr, ~2/CU)
#define BB_T   1024                                // phase-A threads (R14: was 256 -> 12% occ)
#define CHUNK  1600                                // edges per phase-A block (500*1600 = 800000)
#define NBINS  512
#define NPB    196                                 // nodes per bin (512*196 = 100352)
#define CAPB   2048                                // slots/bin (mean 1562, sigma ~40)
#define GB_T   1024                                // gather block threads
#define CURSTRIDE 64                               // ints; 256B per cursor line
// record: .x = sj*512 + (kx0*4+ky0)*32 ; .y = fx12 | fy12<<12 | local<<24
// R12/R13 LESSON (cooperative fusion abandoned): grid-wide co-residency forces
// either 32-VGPR spill (453MB scratch, 301us) or 1-block/CU TLP loss (121us),
// and the coop dispatch adds ~80us uncaptured launch overhead per iteration.

__device__ __forceinline__ unsigned short f2bf(float f) {
    union { float f; unsigned u; } v; v.f = f;
    unsigned u = v.u;
    return (unsigned short)((u + 0x7FFFu + ((u >> 16) & 1u)) >> 16);  // RNE
}
__device__ __forceinline__ float bflo(unsigned u) {
    union { unsigned u; float f; } v; v.u = u << 16; return v.f;
}
__device__ __forceinline__ float bfhi(unsigned u) {
    union { unsigned u; float f; } v; v.u = u & 0xFFFF0000u; return v.f;
}

// ---- phase A: bucket build (R14: 1024 threads/block for latency hiding) ----
__global__ __launch_bounds__(BB_T) void bucket_build(
    const float* __restrict__ edge_attr,
    const int* __restrict__ ei, const int* __restrict__ ej,
    int* __restrict__ cursor, uint2* __restrict__ bkt,
    int* __restrict__ ovfCnt, int* __restrict__ ovf) {
    const int b = blockIdx.x;
    __shared__ int hist[NBINS];            // 2 KB
    __shared__ unsigned rawA[CHUNK];       // 6.4 KB
    __shared__ unsigned rawB[CHUNK];       // 6.4 KB
    __shared__ short rawBin[CHUNK];        // 3.2 KB  (18 KB total -> 2 blocks/CU by threads)
    const int tid = threadIdx.x;
    if (tid < NBINS) hist[tid] = 0;
    __syncthreads();
    const int base = b * CHUNK;

    // pass 1: single edge read, record build, LDS histogram
    for (int i = 0; i < CHUNK; i += BB_T) {
        const int j = i + tid;
        if (j >= CHUNK) continue;                 // CHUNK % BB_T != 0 guard
        const int e = base + j;
        short binS = -1;
        if (e < N_EDGES) {
            const int di = ei[e];
            const int sj = ej[e];
            if (di != sj) {                       // centerIgnore
                const float2 ea = ((const float2*)edge_attr)[e];
                float ux = fminf(fmaxf(ea.x, -1.f), 1.f);
                float uy = fminf(fmaxf(ea.y, -1.f), 1.f);
                float tx = (ux + 1.f) * 1.5f;
                float ty = (uy + 1.f) * 1.5f;
                int kx0 = min((int)tx, 2);
                int ky0 = min((int)ty, 2);
                float fx = tx - (float)kx0;
                float fy = ty - (float)ky0;
                unsigned fx12 = (unsigned)(fx * 4095.f + 0.5f);
                unsigned fy12 = (unsigned)(fy * 4095.f + 0.5f);
                const int bin = di / NPB;
                const unsigned local = (unsigned)(di - bin * NPB);   // < 196
                rawA[j] = (unsigned)(sj * 512 + (kx0 * 4 + ky0) * 32);
                rawB[j] = fx12 | (fy12 << 12) | (local << 24);
                binS = (short)bin;
                atomicAdd(&hist[bin], 1);
            }
        }
        rawBin[j] = binS;
    }
    __syncthreads();

    // pass 2: one returning global atomic per non-empty (block,bin).
    // cursor[k*CURSTRIDE]: each cursor in its own 256B line (L2 channel spread).
    if (tid < NBINS) {
        const int c = hist[tid];
        int g = 0;
        if (c > 0) g = atomicAdd(&cursor[tid * CURSTRIDE], c);
        hist[tid] = tid * CAPB + g;
    }
    __syncthreads();

    // pass 3: replay from LDS, slot via LDS atomic, store 8B record
    for (int i = 0; i < CHUNK; i += BB_T) {
        const int j = i + tid;
        if (j >= CHUNK) continue;
        const int bin = rawBin[j];
        if (bin < 0) continue;
        const int s = atomicAdd(&hist[bin], 1);
        if (s - bin * CAPB < CAPB) {
            bkt[s] = make_uint2(rawA[j], rawB[j]);
        } else {
            const int o = atomicAdd(ovfCnt, 1);
            if (o < OVF_CAP) ovf[o] = base + j;
        }
    }
}

// ---- phase B: gather + input-space accumulation + fused W-contraction ----
// (R9-verified, 45.7us: LDS raw staging, +node stagger, wave scan, 2-deep
//  x prefetch, Wl padded [16][16][20])
__global__ __launch_bounds__(GB_T) void gather_conv(
    const int* __restrict__ cursor, const uint2* __restrict__ bkt,
    const float* __restrict__ x, const float* __restrict__ W,
    float* __restrict__ out,
    const int* __restrict__ ovfCnt, const int* __restrict__ ovf,
    const float* __restrict__ edge_attr, const int* __restrict__ ei,
    const int* __restrict__ ej) {
    const int bin = blockIdx.x;
    const int tid = threadIdx.x;
    __shared__ uint2 sorted[CAPB];
    __shared__ __align__(16) char u_buf[20480];
    __shared__ int h[NPB];
    __shared__ int st[NPB], en[NPB], cur[NPB];
    __shared__ int wsum[4];
    __shared__ float tile[NPB * 16];
    uint2* raw = (uint2*)u_buf;
    float* Wl  = (float*)u_buf;

    for (int j = tid; j < NPB; j += GB_T) h[j] = 0;
    __syncthreads();

    const int cnt = min(cursor[bin * CURSTRIDE], CAPB);
    const int pad = (cnt + NPB <= CAPB) ? 1 : 0;
    const uint2* rb = bkt + (size_t)bin * CAPB;

    for (int p = tid; p < cnt; p += GB_T) {
        uint2 r = rb[p];
        raw[p] = r;
        atomicAdd(&h[r.y >> 24], 1);
    }
    __syncthreads();

    const int lane = tid & 63;
    const int wid  = tid >> 6;
    int c0 = 0, v = 0;
    if (tid < 256) {
        c0 = (tid < NPB) ? h[tid] : 0;
        v = c0;
#pragma unroll
        for (int off = 1; off < 64; off <<= 1) {
            int u = __shfl_up(v, off);
            if (lane >= off) v += u;
        }
        if (lane == 63) wsum[wid] = v;
    }
    __syncthreads();
    if (tid < NPB) {
        int pfx = 0;
#pragma unroll
        for (int w = 0; w < 4; ++w)
            if (w < wid) pfx += wsum[w];
        const int incl = v + pfx;
        const int sh = tid * pad;
        en[tid]  = incl + sh;
        st[tid]  = incl - c0 + sh;
        cur[tid] = incl - c0 + sh;
    }
    __syncthreads();

    for (int p = tid; p < cnt; p += GB_T) {
        uint2 r = raw[p];
        int pos = atomicAdd(&cur[r.y >> 24], 1);
        sorted[pos] = r;
    }
    __syncthreads();

    {
        float4 w = ((const float4*)W)[tid];
        const int k = tid >> 6, i = (tid >> 2) & 15, o4 = tid & 3;
        *(float4*)&Wl[k * 320 + i * 20 + o4 * 4] = w;
    }
    __syncthreads();

    const float U = 1.f / 4095.f;
    const float S = 1.f / 128.f;
    if (tid < 4 * NPB) {
        const int node = tid >> 2;
        const int q4 = tid & 3;
        float t[16][4];
#pragma unroll
        for (int k = 0; k < 16; ++k)
#pragma unroll
            for (int i = 0; i < 4; ++i) t[k][i] = 0.f;

        const int lo = st[node], hi2 = en[node];
        uint2 m = make_uint2(0u, 0u);
        float4 xv = make_float4(0.f, 0.f, 0.f, 0.f);
        if (lo < hi2) {
            m = sorted[lo];
            xv = ((const float4*)x)[(m.x >> 9) * 4 + q4];
        }
        for (int idx = lo; idx < hi2; ++idx) {
            const uint2 mc = m;
            const float4 xc = xv;
            if (idx + 1 < hi2) {
                m = sorted[idx + 1];
                xv = ((const float4*)x)[(m.x >> 9) * 4 + q4];
            }
            const unsigned koff = (mc.x >> 5) & 15u;
            const int kx0 = (int)(koff >> 2);
            const int ky0 = (int)(koff & 3u);
            const float fx = (float)(mc.y & 0xFFFu) * U;
            const float fy = (float)((mc.y >> 12) & 0xFFFu) * U;
            float wx[4], wy[4];
#pragma unroll
            for (int a = 0; a < 4; ++a) {
                wx[a] = (a == kx0) ? (1.f - fx) : ((a == kx0 + 1) ? fx : 0.f);
                wy[a] = (a == ky0) ? (1.f - fy) : ((a == ky0 + 1) ? fy : 0.f);
            }
            const float xr[4] = {xc.x, xc.y, xc.z, xc.w};
#pragma unroll
            for (int kx = 0; kx < 4; ++kx)
#pragma unroll
                for (int ky = 0; ky < 4; ++ky) {
                    const float w = wx[kx] * wy[ky];
#pragma unroll
                    for (int i = 0; i < 4; ++i)
                        t[kx * 4 + ky][i] = fmaf(w, xr[i], t[kx * 4 + ky][i]);
                }
        }

        float po[16];
#pragma unroll
        for (int o = 0; o < 16; ++o) po[o] = 0.f;
#pragma unroll
        for (int k = 0; k < 16; ++k)
#pragma unroll
            for (int il = 0; il < 4; ++il) {
                const float tv = t[k][il];
                const float4* wr = (const float4*)&Wl[k * 320 + (q4 * 4 + il) * 20];
                const float4 w0 = wr[0], w1 = wr[1], w2 = wr[2], w3 = wr[3];
                po[0]  = fmaf(tv, w0.x, po[0]);  po[1]  = fmaf(tv, w0.y, po[1]);
                po[2]  = fmaf(tv, w0.z, po[2]);  po[3]  = fmaf(tv, w0.w, po[3]);
                po[4]  = fmaf(tv, w1.x, po[4]);  po[5]  = fmaf(tv, w1.y, po[5]);
                po[6]  = fmaf(tv, w1.z, po[6]);  po[7]  = fmaf(tv, w1.w, po[7]);
                po[8]  = fmaf(tv, w2.x, po[8]);  po[9]  = fmaf(tv, w2.y, po[9]);
                po[10] = fmaf(tv, w2.z, po[10]); po[11] = fmaf(tv, w2.w, po[11]);
                po[12] = fmaf(tv, w3.x, po[12]); po[13] = fmaf(tv, w3.y, po[13]);
                po[14] = fmaf(tv, w3.z, po[14]); po[15] = fmaf(tv, w3.w, po[15]);
            }

#pragma unroll
        for (int o = 0; o < 16; ++o) {
            po[o] += __shfl_xor(po[o], 1);
            po[o] += __shfl_xor(po[o], 2);
        }
        if (q4 == 0) {
            float* tr = &tile[node * 16];
#pragma unroll
            for (int o = 0; o < 16; ++o) tr[o] = po[o] * S;
        }
    }
    __syncthreads();

    const int m = min(*ovfCnt, OVF_CAP);
    if (m > 0) {
        const int nlo = bin * NPB;
        const int nhi = min(nlo + NPB, N_NODES);
        for (int i = tid; i < m; i += GB_T) {
            const int e = ovf[i];
            const int di = ei[e];
            if (di < nlo || di >= nhi) continue;
            const int sj = ej[e];
            const float2 ea = ((const float2*)edge_attr)[e];
            float ux = fminf(fmaxf(ea.x, -1.f), 1.f);
            float uy = fminf(fmaxf(ea.y, -1.f), 1.f);
            float tx = (ux + 1.f) * 1.5f, ty = (uy + 1.f) * 1.5f;
            int kx0 = min((int)tx, 2), ky0 = min((int)ty, 2);
            float fx = tx - (float)kx0, fy = ty - (float)ky0;
            float wgt[4] = {(1.f-fx)*(1.f-fy)*S, (1.f-fx)*fy*S, fx*(1.f-fy)*S, fx*fy*S};
            int kidx[4] = {kx0*4+ky0, kx0*4+ky0+1, (kx0+1)*4+ky0, (kx0+1)*4+ky0+1};
            const float* xj = x + (size_t)sj * 16;
            float msg[16];
#pragma unroll
            for (int o = 0; o < 16; ++o) msg[o] = 0.f;
#pragma unroll
            for (int p = 0; p < 4; ++p) {
                const float* wk = Wl + kidx[p] * 320;
                for (int ii = 0; ii < 16; ++ii) {
                    float xw = xj[ii] * wgt[p];
#pragma unroll
                    for (int o = 0; o < 16; ++o)
                        msg[o] = fmaf(xw, wk[ii * 20 + o], msg[o]);
                }
            }
            float* tr = &tile[(di - nlo) * 16];
#pragma unroll
            for (int o = 0; o < 16; ++o) atomicAdd(tr + o, msg[o]);
        }
        __syncthreads();
    }

    const int base = bin * NPB * 16;
    const int lim = N_NODES * 16 - base;
    for (int j = tid; j < NPB * 16; j += GB_T)
        if (j < lim) out[base + j] = tile[j];
}

// ============== small-workspace fallbacks (unchanged) ==============
__global__ __launch_bounds__(256) void y_only_kernel(
    const float* __restrict__ x, const float* __restrict__ W,
    unsigned short* __restrict__ Y) {
    const int n = blockIdx.x * 256 + threadIdx.x;
    const int kbase = blockIdx.y * 4;
    if (n >= N_NODES) return;
    const float4* xv = (const float4*)(x + n * 16);
    float4 a = xv[0], b = xv[1], c = xv[2], d = xv[3];
    float xr[16] = {a.x,a.y,a.z,a.w, b.x,b.y,b.z,b.w,
                    c.x,c.y,c.z,c.w, d.x,d.y,d.z,d.w};
    float acc[4][16];
#pragma unroll
    for (int kk = 0; kk < 4; ++kk)
#pragma unroll
        for (int o = 0; o < 16; ++o) acc[kk][o] = 0.f;
#pragma unroll
    for (int i = 0; i < 16; ++i)
#pragma unroll
        for (int kk = 0; kk < 4; ++kk) {
            const float* wrow = W + ((kbase + kk) * 256 + i * 16);
#pragma unroll
            for (int o = 0; o < 16; ++o)
                acc[kk][o] = fmaf(xr[i], wrow[o], acc[kk][o]);
        }
    unsigned short* dst = Y + (size_t)n * 256 + kbase * 16;
#pragma unroll
    for (int kk = 0; kk < 4; ++kk) {
        unsigned pk[8];
#pragma unroll
        for (int q = 0; q < 8; ++q)
            pk[q] = (unsigned)f2bf(acc[kk][2*q]) | ((unsigned)f2bf(acc[kk][2*q+1]) << 16);
        uint4* p = (uint4*)(dst + kk * 16);
        p[0] = make_uint4(pk[0], pk[1], pk[2], pk[3]);
        p[1] = make_uint4(pk[4], pk[5], pk[6], pk[7]);
    }
}

__global__ __launch_bounds__(256) void edge_kernel(
    const float* __restrict__ edge_attr, const int* __restrict__ ei,
    const int* __restrict__ ej, const unsigned short* __restrict__ Y,
    float* __restrict__ out) {
    const int e = blockIdx.x * 256 + threadIdx.x;
    if (e >= N_EDGES) return;
    const int di = ei[e];
    const int sj = ej[e];
    const float2 ea = ((const float2*)edge_attr)[e];
    if (di == sj) return;
    float ux = fminf(fmaxf(ea.x, -1.f), 1.f);
    float uy = fminf(fmaxf(ea.y, -1.f), 1.f);
    float tx = (ux + 1.f) * 1.5f;
    float ty = (uy + 1.f) * 1.5f;
    int kx0 = min((int)tx, 2);
    int ky0 = min((int)ty, 2);
    float fx = tx - (float)kx0;
    float fy = ty - (float)ky0;
    const float S = 1.f / 128.f;
    float w00 = (1.f - fx) * (1.f - fy) * S;
    float w01 = (1.f - fx) * fy * S;
    float w10 = fx * (1.f - fy) * S;
    float w11 = fx * fy * S;
    const unsigned short* base = Y + (size_t)sj * 256 + (kx0 * 4 + ky0) * 16;
    const uint4* pA = (const uint4*)base;
    const uint4* pB = (const uint4*)(base + 64);
    uint4 a0 = pA[0], a1 = pA[1], a2 = pA[2], a3 = pA[3];
    uint4 b0 = pB[0], b1 = pB[1], b2 = pB[2], b3 = pB[3];
    unsigned ra0[8] = {a0.x,a0.y,a0.z,a0.w, a1.x,a1.y,a1.z,a1.w};
    unsigned ra1[8] = {a2.x,a2.y,a2.z,a2.w, a3.x,a3.y,a3.z,a3.w};
    unsigned rb0[8] = {b0.x,b0.y,b0.z,b0.w, b1.x,b1.y,b1.z,b1.w};
    unsigned rb1[8] = {b2.x,b2.y,b2.z,b2.w, b3.x,b3.y,b3.z,b3.w};
    float* o16 = out + (size_t)di * 16;
#pragma unroll
    for (int q = 0; q < 8; ++q) {
        float m0 = bflo(ra0[q]) * w00 + bflo(ra1[q]) * w01
                 + bflo(rb0[q]) * w10 + bflo(rb1[q]) * w11;
        float m1 = bfhi(ra0[q]) * w00 + bfhi(ra1[q]) * w01
                 + bfhi(rb0[q]) * w10 + bfhi(rb1[q]) * w11;
        atomicAdd(o16 + 2 * q, m0);
        atomicAdd(o16 + 2 * q + 1, m1);
    }
}

__global__ __launch_bounds__(256) void edge_direct(
    const float* __restrict__ x, const float* __restrict__ edge_attr,
    const float* __restrict__ W, const int* __restrict__ ei,
    const int* __restrict__ ej, float* __restrict__ out) {
    const int e = blockIdx.x * 256 + threadIdx.x;
    if (e >= N_EDGES) return;
    const int di = ei[e];
    const int sj = ej[e];
    const float2 ea = ((const float2*)edge_attr)[e];
    if (di == sj) return;
    float ux = fminf(fmaxf(ea.x, -1.f), 1.f);
    float uy = fminf(fmaxf(ea.y, -1.f), 1.f);
    float tx = (ux + 1.f) * 1.5f, ty = (uy + 1.f) * 1.5f;
    int kx0 = min((int)tx, 2), ky0 = min((int)ty, 2);
    float fx = tx - (float)kx0, fy = ty - (float)ky0;
    const float S = 1.f / 128.f;
    float wgt[4] = {(1.f-fx)*(1.f-fy)*S, (1.f-fx)*fy*S, fx*(1.f-fy)*S, fx*fy*S};
    int kidx[4] = {kx0*4+ky0, kx0*4+ky0+1, (kx0+1)*4+ky0, (kx0+1)*4+ky0+1};
    const float* xj = x + (size_t)sj * 16;
    float xr[16];
#pragma unroll
    for (int i = 0; i < 16; ++i) xr[i] = xj[i];
    float msg[16];
#pragma unroll
    for (int o = 0; o < 16; ++o) msg[o] = 0.f;
#pragma unroll
    for (int p = 0; p < 4; ++p) {
        const float* wk = W + kidx[p] * 256;
#pragma unroll
        for (int i = 0; i < 16; ++i) {
            float xw = xr[i] * wgt[p];
#pragma unroll
            for (int o = 0; o < 16; ++o)
                msg[o] = fmaf(xw, wk[i * 16 + o], msg[o]);
        }
    }
    float* o16 = out + (size_t)di * 16;
#pragma unroll
    for (int o = 0; o < 16; ++o) atomicAdd(o16 + o, msg[o]);
}

extern "C" void kernel_launch(void* const* d_in, const int* in_sizes, int n_in,
                              void* d_out, int out_size, void* d_ws, size_t ws_size,
                              hipStream_t stream) {
    const float* x         = (const float*)d_in[0];
    const float* edge_attr = (const float*)d_in[1];
    const float* W         = (const float*)d_in[2];
    const int*   ei        = (const int*)d_in[3];
    const int*   ej        = (const int*)d_in[4];
    float* out = (float*)d_out;
    char* ws = (char*)d_ws;

    // ---- bin-path workspace (16B aligned); cursor padded to 256B/bin ----
    const size_t oCur    = 0;                                   // NBINS*256 = 131,072
    const size_t oOvfCnt = oCur + (size_t)NBINS * CURSTRIDE * 4;// 16
    const size_t oOvf    = oOvfCnt + 16;                        // OVF_CAP*4 = 262,144
    const size_t oBkt    = oOvf + (size_t)OVF_CAP * 4;          // NBINS*CAPB*8 = 8,388,608
    const size_t total   = oBkt + (size_t)NBINS * CAPB * 8;     // ~8.8 MB

    if (ws_size >= total) {
        int*   cursor = (int*)(ws + oCur);
        int*   ovfCnt = (int*)(ws + oOvfCnt);
        int*   ovf    = (int*)(ws + oOvf);
        uint2* bkt    = (uint2*)(ws + oBkt);

        hipMemsetAsync(cursor, 0, (size_t)NBINS * CURSTRIDE * 4 + 16, stream);
        bucket_build<<<GA, BB_T, 0, stream>>>(
            edge_attr, ei, ej, cursor, bkt, ovfCnt, ovf);
        gather_conv<<<NBINS, GB_T, 0, stream>>>(
            cursor, bkt, x, W, out, ovfCnt, ovf, edge_attr, ei, ej);
        return;
    }

    const size_t yBytes = (size_t)N_NODES * 512;
    if (ws_size >= yBytes) {
        hipMemsetAsync(d_out, 0, (size_t)out_size * sizeof(float), stream);
        unsigned short* Y = (unsigned short*)d_ws;
        dim3 gA(NBY, 4);
        y_only_kernel<<<gA, 256, 0, stream>>>(x, W, Y);
        edge_kernel<<<HBLK, 256, 0, stream>>>(edge_attr, ei, ej, Y, out);
    } else {
        hipMemsetAsync(d_out, 0, (size_t)out_size * sizeof(float), stream);
        edge_direct<<<HBLK, 256, 0, stream>>>(x, edge_attr, W, ei, ej, out);
    }
}